// Round 1
// baseline (107.697 us; speedup 1.0000x reference)
//
#include <hip/hip_runtime.h>

// Elementwise: out[i] = x[i] > 0 ? x[i]*x[i] : x[i]
// N = 2^26 fp32. Memory-bound: 512 MB total traffic, ceiling ~85us @ 6.3 TB/s.

__global__ void sq_pos_kernel(const float4* __restrict__ x, float4* __restrict__ out,
                              long long nvec) {
    long long stride = (long long)gridDim.x * blockDim.x;
    for (long long i = (long long)blockIdx.x * blockDim.x + threadIdx.x; i < nvec; i += stride) {
        float4 v = x[i];
        float4 r;
        r.x = v.x > 0.0f ? v.x * v.x : v.x;
        r.y = v.y > 0.0f ? v.y * v.y : v.y;
        r.z = v.z > 0.0f ? v.z * v.z : v.z;
        r.w = v.w > 0.0f ? v.w * v.w : v.w;
        out[i] = r;
    }
}

extern "C" void kernel_launch(void* const* d_in, const int* in_sizes, int n_in,
                              void* d_out, int out_size, void* d_ws, size_t ws_size,
                              hipStream_t stream) {
    const float4* x = (const float4*)d_in[0];
    float4* out = (float4*)d_out;
    long long n = in_sizes[0];
    long long nvec = n / 4;  // N = 2^26, divisible by 4

    const int block = 256;
    // Memory-bound: cap grid at ~8 blocks/CU * 256 CUs, grid-stride the rest.
    long long want = (nvec + block - 1) / block;
    int grid = (int)(want < 2048 ? want : 2048);

    sq_pos_kernel<<<grid, block, 0, stream>>>(x, out, nvec);

    // Handle any non-multiple-of-4 tail (not expected for N=2^26, but safe):
    long long tail_start = nvec * 4;
    if (tail_start < n) {
        // single tiny block for the remainder
        struct Tail {
            static __global__ void k(const float* __restrict__ x, float* __restrict__ o,
                                     long long start, long long n) {
                long long i = start + threadIdx.x;
                if (i < n) { float v = x[i]; o[i] = v > 0.0f ? v * v : v; }
            }
        };
        hipLaunchKernelGGL(Tail::k, dim3(1), dim3(64), 0, stream,
                           (const float*)d_in[0], (float*)d_out, tail_start, n);
    }
}